// Round 1
// baseline (262.048 us; speedup 1.0000x reference)
//
#include <hip/hip_runtime.h>
#include <math.h>

#define D 172
#define D4 43          // D/4 float4s per row
#define RPB 8          // batch rows per block
#define TPB 192        // threads per block (3 waves; threads 0..171 compute)

// ---------------------------------------------------------------------------
// Kernel 1: bulk copy memory -> out[0:N*D], last_update -> out[N*D:N*D+N]
// Pure HBM-bound float4 grid-stride copy. N*D and N are both divisible by 4,
// and out + N*D floats is 16B-aligned (344e6 % 16 == 0).
// ---------------------------------------------------------------------------
__global__ void copy_kernel(const float4* __restrict__ mem,
                            const float4* __restrict__ lu,
                            float4* __restrict__ out,
                            long memf4, long totalf4) {
    long stride = (long)gridDim.x * blockDim.x;
    for (long i = (long)blockIdx.x * blockDim.x + threadIdx.x; i < totalf4; i += stride) {
        out[i] = (i < memf4) ? mem[i] : lu[i - memf4];
    }
}

// ---------------------------------------------------------------------------
// Kernel 2: GRU cell for the 4096 touched rows + last-write-wins scatter.
// One block = 8 batch rows. x,h staged in LDS; thread d (<172) computes all
// 6 dot products (i_r,i_z,i_n,h_r,h_z,h_n) for all 8 rows via float4 weight
// loads (weights L2-resident). Duplicate suppression: row i scatters only if
// no j>i has the same node id (scan of the global id list, O(B/TPB) per row).
// ---------------------------------------------------------------------------
__global__ __launch_bounds__(TPB) void gru_kernel(
    const int* __restrict__ ids, const float* __restrict__ msg,
    const float* __restrict__ ts, const float* __restrict__ mem,
    const float* __restrict__ w_ih, const float* __restrict__ w_hh,
    const float* __restrict__ b_ih, const float* __restrict__ b_hh,
    float* __restrict__ out_mem, float* __restrict__ out_lu,
    int B) {
    __shared__ float4 sx4[RPB][D4];
    __shared__ float4 sh4[RPB][D4];
    __shared__ int   s_id[RPB];
    __shared__ float s_ts[RPB];
    __shared__ int   s_dup[RPB];

    const int tid  = threadIdx.x;
    const int base = blockIdx.x * RPB;

    if (tid < RPB) {
        s_id[tid]  = ids[base + tid];
        s_ts[tid]  = ts[base + tid];
        s_dup[tid] = 0;
    }
    __syncthreads();

    float* sx = (float*)sx4;
    float* sh = (float*)sh4;
    // stage x (messages) and h (gathered memory rows)
    #pragma unroll
    for (int r = 0; r < RPB; ++r) {
        if (tid < D) {
            sx[r * D + tid] = msg[(long)(base + r) * D + tid];
            sh[r * D + tid] = mem[(long)s_id[r] * D + tid];
        }
    }
    // duplicate scan: row r loses if any later batch index has the same id
    for (int r = 0; r < RPB; ++r) {
        int my = s_id[r];
        for (int j = base + r + 1 + tid; j < B; j += TPB) {
            if (ids[j] == my) { s_dup[r] = 1; break; }
        }
    }
    __syncthreads();

    float acc[6][RPB];
    #pragma unroll
    for (int g = 0; g < 6; ++g)
        #pragma unroll
        for (int r = 0; r < RPB; ++r) acc[g][r] = 0.0f;

    const int d = tid;
    if (d < D) {
        const float4* wi0 = (const float4*)(w_ih + (long)(0 * D + d) * D);
        const float4* wi1 = (const float4*)(w_ih + (long)(1 * D + d) * D);
        const float4* wi2 = (const float4*)(w_ih + (long)(2 * D + d) * D);
        const float4* wh0 = (const float4*)(w_hh + (long)(0 * D + d) * D);
        const float4* wh1 = (const float4*)(w_hh + (long)(1 * D + d) * D);
        const float4* wh2 = (const float4*)(w_hh + (long)(2 * D + d) * D);

        for (int k = 0; k < D4; ++k) {
            float4 a0 = wi0[k], a1 = wi1[k], a2 = wi2[k];
            float4 c0 = wh0[k], c1 = wh1[k], c2 = wh2[k];
            #pragma unroll
            for (int r = 0; r < RPB; ++r) {
                float4 xv = sx4[r][k];
                float4 hv = sh4[r][k];
                acc[0][r] += a0.x * xv.x + a0.y * xv.y + a0.z * xv.z + a0.w * xv.w;
                acc[1][r] += a1.x * xv.x + a1.y * xv.y + a1.z * xv.z + a1.w * xv.w;
                acc[2][r] += a2.x * xv.x + a2.y * xv.y + a2.z * xv.z + a2.w * xv.w;
                acc[3][r] += c0.x * hv.x + c0.y * hv.y + c0.z * hv.z + c0.w * hv.w;
                acc[4][r] += c1.x * hv.x + c1.y * hv.y + c1.z * hv.z + c1.w * hv.w;
                acc[5][r] += c2.x * hv.x + c2.y * hv.y + c2.z * hv.z + c2.w * hv.w;
            }
        }

        float bir = b_ih[d], biz = b_ih[D + d], bin_ = b_ih[2 * D + d];
        float bhr = b_hh[d], bhz = b_hh[D + d], bhn  = b_hh[2 * D + d];
        #pragma unroll
        for (int r = 0; r < RPB; ++r) {
            float i_r = acc[0][r] + bir;
            float i_z = acc[1][r] + biz;
            float i_n = acc[2][r] + bin_;
            float h_r = acc[3][r] + bhr;
            float h_z = acc[4][r] + bhz;
            float h_n = acc[5][r] + bhn;
            float rg = 1.0f / (1.0f + expf(-(i_r + h_r)));
            float zg = 1.0f / (1.0f + expf(-(i_z + h_z)));
            float ng = tanhf(i_n + rg * h_n);
            float hv = sh[r * D + d];
            float outv = (1.0f - zg) * ng + zg * hv;
            if (!s_dup[r]) out_mem[(long)s_id[r] * D + d] = outv;
        }
    }
    if (tid < RPB && !s_dup[tid]) out_lu[s_id[tid]] = s_ts[tid];
}

extern "C" void kernel_launch(void* const* d_in, const int* in_sizes, int n_in,
                              void* d_out, int out_size, void* d_ws, size_t ws_size,
                              hipStream_t stream) {
    const int*   node_ids    = (const int*)d_in[0];
    const float* messages    = (const float*)d_in[1];
    const float* timestamps  = (const float*)d_in[2];
    const float* memory      = (const float*)d_in[3];
    const float* last_update = (const float*)d_in[4];
    const float* w_ih        = (const float*)d_in[5];
    const float* w_hh        = (const float*)d_in[6];
    const float* b_ih        = (const float*)d_in[7];
    const float* b_hh        = (const float*)d_in[8];
    float* out = (float*)d_out;

    const int B = in_sizes[0];          // 4096
    const int N = in_sizes[4];          // 500000
    const long memf   = (long)N * D;    // 86,000,000
    const long memf4  = memf / 4;
    const long totalf4 = (memf + N) / 4;

    copy_kernel<<<2048, 256, 0, stream>>>((const float4*)memory,
                                          (const float4*)last_update,
                                          (float4*)out, memf4, totalf4);

    gru_kernel<<<B / RPB, TPB, 0, stream>>>(node_ids, messages, timestamps, memory,
                                            w_ih, w_hh, b_ih, b_hh,
                                            out, out + memf, B);
}